// Round 7
// baseline (218.430 us; speedup 1.0000x reference)
//
#include <hip/hip_runtime.h>

// PartialGConv: partial temporal conv (TK=9, pad 4) + mask-ratio + graph einsum.
// FUSED kernel: bf16 implicit-GEMM (MFMA 16x16x32, BM=192 x BN=200(8t) x K=576)
// + (k,v)-contraction epilogue. B staged ONCE per block: the 408-row tv-window
// (all 9 dt shifts) lives in LDS; K-loop stages only A (12KB/step, 2-ring).
//
// ws layout (bytes):
//   xmr  u16[32][6656][64]  @0          x*mask bf16 row-major, padded rows
//   wb   u16[192][576]      @27,262,976 weights bf16, k=dt*64+cin, 16B-slot swizzled
//   msum f32[32][6400]      @27,484,160 sum_cin mask
//   s    f32[32][6400]      @28,303,360 576/(upd+eps)*uc^2
//   mr   f32[32][6400]      @29,122,560 mask_ratio
//   mb   f32[32][6400]      @29,941,760 m_bool
//   Bc   f32[32][3][256][25]@30,760,960 sum_v uc*A[k,v,w]

typedef unsigned short u16;
typedef unsigned int u32;
typedef short short8 __attribute__((ext_vector_type(8)));
typedef float f32x4 __attribute__((ext_vector_type(4)));

#define TV 6400
#define KC 192
#define KDIM 576
#define NPADT 6656          // 100 front pad + 6400 + 156 back pad
#define Y_SIZE 13107200
#define MB_OFF 13109075     // Y_SIZE + 1875

#define OFF_WB   27262976
#define OFF_MSUM 27484160
#define OFF_S    28303360
#define OFF_MR   29122560
#define OFF_MB   29941760
#define OFF_BC   30760960

// LDS map (76,800 B total)
#define L_XWIN 0            // u16[408][64], slot-swizzled: 52,224 B
#define L_ARING 52224       // 2 x u16[192][32] = 2 x 12,288 B
#define L_AS   52224        // epilogue alias: f32[3][25][28] 8,400
#define L_BCS  60624        // f32[3][8][25] 2,400
#define L_MRS  63024        // f32[8][25] 800
#define L_MBS  63824        // f32[8][25] 800
#define L_BIAS 64624        // f32[192] 768
#define L_SS   65392        // f32[200] 800

#define VMCNT(N) asm volatile("s_waitcnt vmcnt(" #N ")" ::: "memory")

__device__ __forceinline__ u16 f2bf(float f) {
  u32 u = __builtin_bit_cast(u32, f);
  u = (u + 0x7FFFu + ((u >> 16) & 1u)) >> 16;   // RTNE
  return (u16)u;
}
__device__ __forceinline__ float bf2f(u16 h) {
  return __builtin_bit_cast(float, (u32)h << 16);
}
__device__ __forceinline__ void gload_lds16(const u16* g, u16* l) {
  __builtin_amdgcn_global_load_lds(
      (const __attribute__((address_space(1))) u32*)(const void*)g,
      (__attribute__((address_space(3))) u32*)(void*)l, 16, 0, 0);
}

// ---- zero the temporal pad rows of xmr --------------------------------------
__global__ void k_pad(u16* __restrict__ xmr) {
  int i = blockIdx.x * 256 + threadIdx.x;       // 65536 uint4
  if (i >= 65536) return;
  int n = i >> 11, r = i & 2047;                // 256 pad rows x 8 uint4
  int row = r >> 3, c = r & 7;
  int tvrow = (row < 100) ? row : (6400 + row); // front 0..99 / back 6500..6655
  uint4 z; z.x = z.y = z.z = z.w = 0u;
  *(uint4*)(xmr + ((size_t)n * NPADT + tvrow) * 64 + c * 8) = z;
}

// ---- xmr = bf16(x*mask) row-major [tvp][64] + msum = sum_cin mask ------------
__global__ void k_xmT(const float* __restrict__ x, const float* __restrict__ mask,
                      u16* __restrict__ xmr, float* __restrict__ msum) {
  const int tvb = blockIdx.x, n = blockIdx.y;   // grid (100, 32), block 256
  const int tvl = threadIdx.x & 63, q = threadIdx.x >> 6;  // 4 quads of 16 cin
  const int tv = tvb * 64 + tvl;
  const float* xp = x + ((size_t)n * 64 + q * 16) * TV + tv;
  const float* mp = mask + ((size_t)n * 64 + q * 16) * TV + tv;
  u16 vals[16];
  float msacc = 0.f;
#pragma unroll
  for (int j = 0; j < 16; ++j) {                // coalesced: lanes = consecutive tv
    float xv = xp[(size_t)j * TV];
    float mv = mp[(size_t)j * TV];
    msacc += mv;
    vals[j] = f2bf(xv * mv);
  }
  uint4 lo, hi;
  lo.x = vals[0] | ((u32)vals[1] << 16);  lo.y = vals[2] | ((u32)vals[3] << 16);
  lo.z = vals[4] | ((u32)vals[5] << 16);  lo.w = vals[6] | ((u32)vals[7] << 16);
  hi.x = vals[8] | ((u32)vals[9] << 16);  hi.y = vals[10] | ((u32)vals[11] << 16);
  hi.z = vals[12] | ((u32)vals[13] << 16); hi.w = vals[14] | ((u32)vals[15] << 16);
  u16* dst = xmr + ((size_t)n * NPADT + 100 + tv) * 64 + q * 16;
  *(uint4*)dst = lo;
  *(uint4*)(dst + 8) = hi;
  __shared__ float red[4][64];
  red[q][tvl] = msacc;
  __syncthreads();
  if (q == 0) msum[n * TV + tv] = red[0][tvl] + red[1][tvl] + red[2][tvl] + red[3][tvl];
}

// ---- wb[kc][k=dt*64+cin], bf16, 16B-slot XOR pre-swizzle (by (kc>>1)&3) -----
__global__ void k_w(const float* __restrict__ weight, u16* __restrict__ wb) {
  int i = blockIdx.x * 256 + threadIdx.x;      // 110592
  if (i >= 110592) return;
  int kc = i / KDIM, k = i % KDIM;
  int cin = k & 63, dt = k >> 6;
  float v = weight[(kc * 64 + cin) * 9 + dt];
  int phys = (k & ~31) | ((((k >> 3) & 3) ^ ((kc >> 1) & 3)) << 3) | (k & 7);
  wb[kc * KDIM + phys] = f2bf(v);
}

// ---- per (n,t): upd -> s, mask_ratio, m_bool, Bc ----------------------------
__global__ void k_prep(const float* __restrict__ msum, const float* __restrict__ A_g,
                       float* __restrict__ s_ws, float* __restrict__ mr_ws,
                       float* __restrict__ mb_ws, float* __restrict__ Bc_ws) {
  int b = blockIdx.x;                          // 8192 = n*256 + t
  int n = b >> 8, t = b & 255;
  int tid = threadIdx.x;                       // 64
  __shared__ float uc[25];
  if (tid < 25) {
    float upd = 0.f;
    for (int dt = 0; dt < 9; ++dt) {
      int tt = t + dt - 4;
      if (tt >= 0 && tt < 256) upd += msum[n * TV + tt * 25 + tid];
    }
    float u_c = fminf(fmaxf(upd, 0.f), 1.f);
    float ratio = 576.f / (upd + 1e-8f);
    s_ws[n * TV + t * 25 + tid] = ratio * u_c * u_c;  // coeff of raw in out
    uc[tid] = u_c;
  }
  __syncthreads();
  if (tid < 25) {
    int w = tid;
    float M = 0.f;
    for (int k = 0; k < 3; ++k) {
      float acc = 0.f;
      for (int v = 0; v < 25; ++v) acc += uc[v] * A_g[(k * 25 + v) * 25 + w];
      Bc_ws[((size_t)(n * 3 + k) * 256 + t) * 25 + w] = acc;
      M += acc;
    }
    float mbv = (M != 0.f) ? 1.f : 0.f;
    mr_ws[n * TV + t * 25 + w] = mbv / (M + 1e-8f);
    mb_ws[n * TV + t * 25 + w] = mbv;
  }
}

// ---- FUSED: implicit-GEMM + (k,v)-contraction + coalesced epilogue ----------
// Block (tg, n): B window (408 rows x 64 cin, all dt shifts) staged ONCE into
// LDS (XOR slot-swizzle via per-lane global src); K-loop stages only A (2-ring).
// 8 waves = 4(M) x 2(N); wn=0: 7 col-frags (0-111), wn=1: 6 (112-207).
__global__ __launch_bounds__(512, 4) void k_fused(
    const u16* __restrict__ xmr, const u16* __restrict__ wb,
    const float* __restrict__ s_g, const float* __restrict__ A_g,
    const float* __restrict__ Bc_g, const float* __restrict__ mr_g,
    const float* __restrict__ mb_g, const float* __restrict__ bias_g,
    float* __restrict__ out) {
  __shared__ __align__(16) char ring[76800];

  const int tid = threadIdx.x;
  const int tg = blockIdx.x;                  // 0..31 (8-t group)
  const int n = blockIdx.y;                   // 0..31
  const int tv0 = tg * 200;
  const int lane = tid & 63, wid = tid >> 6;
  const int wm = wid >> 1, wn = wid & 1;
  const int lrow = lane & 15, lgrp = lane >> 4;
  const int nf = 7 - wn, colb = wn * 112;

  const u16* xmn = xmr + (size_t)n * NPADT * 64;
  u16* xwin = (u16*)(ring + L_XWIN);

  f32x4 acc[3][7] = {};

  // ---- prologue: stage whole B window (51 loads) + A step 0 (12 loads) ------
  {
    // window rows [tv0, tv0+408) in padded coords; tv0 % 8 == 0 so the
    // logical-slot swizzle key (row & 7) is position-invariant.
    const int srow_g = lane >> 3, sl = (lane & 7) ^ (lane >> 3);  // per-lane
    for (int t = wid; t < 51; t += 8) {
      const u16* src = xmn + ((size_t)(tv0 + t * 8 + srow_g) * 64 + sl * 8);
      gload_lds16(src, xwin + t * 512);
    }
    u16* abase = (u16*)(ring + L_ARING);
    for (int t = wid; t < 12; t += 8) {
      const u16* src = wb + (size_t)(t * 16 + (lane >> 2)) * KDIM + (lane & 3) * 8;
      gload_lds16(src, abase + t * 512);
    }
  }
  VMCNT(0);
  __builtin_amdgcn_s_barrier();
  asm volatile("" ::: "memory");

  // ---- K-loop: 18 steps; only A staged per step --------------------------
  for (int ks = 0; ks < 18; ++ks) {
    const int cur = ks & 1;
    if (ks < 17) {                             // stage A(ks+1) into buf cur^1
      u16* abase = (u16*)(ring + L_ARING + (cur ^ 1) * 12288);
      for (int t = wid; t < 12; t += 8) {
        const u16* src = wb + (size_t)(t * 16 + (lane >> 2)) * KDIM + (ks + 1) * 32 + (lane & 3) * 8;
        gload_lds16(src, abase + t * 512);
      }
    }

    const u16* abuf = (const u16*)(ring + L_ARING + cur * 12288);
    short8 af[3];
#pragma unroll
    for (int m = 0; m < 3; ++m) {
      int arow = wm * 48 + m * 16 + lrow;
      af[m] = *(const short8*)&abuf[arow * 32 + ((lgrp ^ ((arow >> 1) & 3)) << 3)];
    }
    const int dt = ks >> 1;
    const int rbase = 100 + (dt - 4) * 25 + colb + lrow;   // lds row for ct=0
    const int slb = (ks & 1) * 4 + lgrp;                   // logical 16B slot
#pragma unroll
    for (int ct = 0; ct < 7; ++ct) {
      if (ct < nf) {
        int srow = rbase + ct * 16;
        short8 bfr = *(const short8*)&xwin[srow * 64 + ((slb ^ (srow & 7)) << 3)];
#pragma unroll
        for (int m = 0; m < 3; ++m)
          acc[m][ct] = __builtin_amdgcn_mfma_f32_16x16x32_bf16(af[m], bfr, acc[m][ct], 0, 0, 0);
      }
    }

    if (ks < 17) {
      VMCNT(0);                        // own A(ks+1) loads landed (overlap=compute)
      __builtin_amdgcn_s_barrier();    // all waves done reading abuf[cur]
      asm volatile("" ::: "memory");
    }
  }

  // ---- epilogue: load misc into A-ring alias, then contraction -------------
  __syncthreads();                     // all xwin/A reads done; safe to alias
  float* Asf   = (float*)(ring + L_AS);
  float* Bcsf  = (float*)(ring + L_BCS);
  float* mrsf  = (float*)(ring + L_MRS);
  float* mbsf  = (float*)(ring + L_MBS);
  float* biasf = (float*)(ring + L_BIAS);
  float* ssf   = (float*)(ring + L_SS);
  for (int i = tid; i < 2100; i += 512) {
    int k = i / 700, r = (i % 700) / 28, w = i % 28;
    Asf[i] = (w < 25) ? A_g[(k * 25 + r) * 25 + w] : 0.f;
  }
  for (int i = tid; i < 600; i += 512) {
    int k = i / 200, t = (i % 200) / 25, w = i % 25;
    Bcsf[i] = Bc_g[((size_t)(n * 3 + k) * 256 + tg * 8 + t) * 25 + w];
  }
  for (int i = tid; i < 200; i += 512) {
    mrsf[i] = mr_g[n * TV + tv0 + i];
    mbsf[i] = mb_g[n * TV + tv0 + i];
    ssf[i]  = s_g[n * TV + tv0 + i];
  }
  if (tid < 192) biasf[tid] = bias_g[tid];
  __syncthreads();

  u16 (*Cl)[210] = (u16(*)[210])ring;          // alias xwin; stride 105 dw
  float (*Ys)[201] = (float(*)[201])ring;      // alias, barrier-separated
  const int c = tid & 63, tl = tid >> 6;
  f32x4 a4[7] = {};

  for (int k = 0; k < 3; ++k) {
    __syncthreads();                           // prev Cl reads done
#pragma unroll
    for (int m = 0; m < 3; ++m) {
      int R = wm * 48 + m * 16 + lgrp * 4;
      if ((R >> 6) == k) {
#pragma unroll
        for (int ct = 0; ct < 7; ++ct) {
          if (ct < nf) {
            int col = colb + ct * 16 + lrow;
            if (col < 200) {
#pragma unroll
              for (int r = 0; r < 4; ++r)
                Cl[(R & 63) + r][col] = f2bf(acc[m][ct][r] * ssf[col]);
            }
          }
        }
      }
    }
    __syncthreads();
#pragma unroll 5
    for (int v = 0; v < 25; ++v) {
      float cs = bf2f(Cl[c][tl * 25 + v]);
      const f32x4* ar = (const f32x4*)&Asf[(k * 25 + v) * 28];   // broadcast
#pragma unroll
      for (int q = 0; q < 7; ++q) a4[q] += cs * ar[q];
    }
  }

  // finalize per-thread y values
  float yv[25];
  {
    const float b0 = biasf[c], b1 = biasf[64 + c], b2 = biasf[128 + c];
#pragma unroll
    for (int w = 0; w < 25; ++w) {
      float bt = b0 * Bcsf[tl * 25 + w] + b1 * Bcsf[200 + tl * 25 + w] +
                 b2 * Bcsf[400 + tl * 25 + w];
      yv[w] = (a4[w >> 2][w & 3] + bt) * mrsf[tl * 25 + w];
    }
  }

  // y: two half-c passes through Ys (aliases Cl), coalesced 200-float runs
  const size_t base_n = (size_t)(n * 64) * 6400 + tv0;
#pragma unroll
  for (int half = 0; half < 2; ++half) {
    __syncthreads();                       // Cl/prior-Ys reads complete
    if ((c >> 5) == half) {
      float* yrow = &Ys[c & 31][tl * 25];
#pragma unroll
      for (int w = 0; w < 25; ++w) yrow[w] = yv[w];
    }
    __syncthreads();
    for (int i = tid; i < 6400; i += 512) {
      int ch = i / 200, j = i % 200;
      out[base_n + (size_t)(half * 32 + ch) * 6400 + j] = Ys[ch][j];
    }
  }

  // m_bool: c-independent broadcast, direct coalesced stores
  for (int i = tid; i < 12800; i += 512) {
    int cc = i / 200, j = i % 200;
    out[MB_OFF + base_n + (size_t)cc * 6400 + j] = mbsf[j];
  }
}

extern "C" void kernel_launch(void* const* d_in, const int* in_sizes, int n_in,
                              void* d_out, int out_size, void* d_ws, size_t ws_size,
                              hipStream_t stream) {
  const float* x      = (const float*)d_in[0];
  const float* A      = (const float*)d_in[1];
  const float* mask   = (const float*)d_in[2];
  const float* weight = (const float*)d_in[3];
  const float* bias   = (const float*)d_in[4];
  float* out = (float*)d_out;
  char* ws = (char*)d_ws;

  u16*   xmr   = (u16*)(ws);
  u16*   wb    = (u16*)(ws + OFF_WB);
  float* msum  = (float*)(ws + OFF_MSUM);
  float* s_ws  = (float*)(ws + OFF_S);
  float* mr_ws = (float*)(ws + OFF_MR);
  float* mb_ws = (float*)(ws + OFF_MB);
  float* Bc_ws = (float*)(ws + OFF_BC);

  k_pad<<<256, 256, 0, stream>>>(xmr);
  k_xmT<<<dim3(100, 32), 256, 0, stream>>>(x, mask, xmr, msum);
  k_w<<<432, 256, 0, stream>>>(weight, wb);
  k_prep<<<8192, 64, 0, stream>>>(msum, A, s_ws, mr_ws, mb_ws, Bc_ws);

  hipMemcpyAsync(out + Y_SIZE, A, 1875 * sizeof(float),
                 hipMemcpyDeviceToDevice, stream);

  k_fused<<<dim3(32, 32), 512, 0, stream>>>(xmr, wb, s_ws, A, Bc_ws, mr_ws,
                                            mb_ws, bias, out);
}

// Round 8
// 203.377 us; speedup vs baseline: 1.0740x; 1.0740x over previous
//
#include <hip/hip_runtime.h>

// PartialGConv: partial temporal conv (TK=9, pad 4) + mask-ratio + graph einsum.
// FUSED kernel: bf16 implicit-GEMM (MFMA 16x16x32, BM=192 x BN=208(8t) x K=576)
// + (k,v)-contraction epilogue. B window (408 rows, all 9 dt shifts) staged ONCE
// per block; K-loop stages only A (2-ring). 1024 threads / 16 waves (4M x 4N):
// acc[3][4] = 48 regs/thread -> NO spill under the 128-VGPR budget (r7 lesson:
// 512-thr variant spilled ~27 regs/thread; VMCNT(0) drained scratch every step).
//
// ws layout (bytes):
//   xmr  u16[32][6656][64]  @0          x*mask bf16 row-major, padded rows
//   wb   u16[192][576]      @27,262,976 weights bf16, k=dt*64+cin, 16B-slot swizzled
//   msum f32[32][6400]      @27,484,160 sum_cin mask
//   s    f32[32][6400]      @28,303,360 576/(upd+eps)*uc^2
//   mr   f32[32][6400]      @29,122,560 mask_ratio
//   mb   f32[32][6400]      @29,941,760 m_bool
//   Bc   f32[32][3][256][25]@30,760,960 sum_v uc*A[k,v,w]

typedef unsigned short u16;
typedef unsigned int u32;
typedef short short8 __attribute__((ext_vector_type(8)));
typedef float f32x4 __attribute__((ext_vector_type(4)));

#define TV 6400
#define KC 192
#define KDIM 576
#define NPADT 6656          // 100 front pad + 6400 + 156 back pad
#define Y_SIZE 13107200
#define MB_OFF 13109075     // Y_SIZE + 1875

#define OFF_WB   27262976
#define OFF_MSUM 27484160
#define OFF_S    28303360
#define OFF_MR   29122560
#define OFF_MB   29941760
#define OFF_BC   30760960

// LDS map (76,800 B total)
#define L_XWIN 0            // u16[408][64], slot-swizzled: 52,224 B
#define L_ARING 52224       // 2 x u16[192][32] = 2 x 12,288 B
#define L_AS   52224        // epilogue alias: f32[3][25][28] 8,400
#define L_BCS  60624        // f32[3][8][25] 2,400
#define L_MRS  63024        // f32[8][25] 800
#define L_MBS  63824        // f32[8][25] 800
#define L_BIAS 64624        // f32[192] 768
#define L_SS   65392        // f32[200] 800

#define VMCNT(N) asm volatile("s_waitcnt vmcnt(" #N ")" ::: "memory")

__device__ __forceinline__ u16 f2bf(float f) {
  u32 u = __builtin_bit_cast(u32, f);
  u = (u + 0x7FFFu + ((u >> 16) & 1u)) >> 16;   // RTNE
  return (u16)u;
}
__device__ __forceinline__ float bf2f(u16 h) {
  return __builtin_bit_cast(float, (u32)h << 16);
}
__device__ __forceinline__ void gload_lds16(const u16* g, u16* l) {
  __builtin_amdgcn_global_load_lds(
      (const __attribute__((address_space(1))) u32*)(const void*)g,
      (__attribute__((address_space(3))) u32*)(void*)l, 16, 0, 0);
}

// ---- zero the temporal pad rows of xmr --------------------------------------
__global__ void k_pad(u16* __restrict__ xmr) {
  int i = blockIdx.x * 256 + threadIdx.x;       // 65536 uint4
  if (i >= 65536) return;
  int n = i >> 11, r = i & 2047;                // 256 pad rows x 8 uint4
  int row = r >> 3, c = r & 7;
  int tvrow = (row < 100) ? row : (6400 + row); // front 0..99 / back 6500..6655
  uint4 z; z.x = z.y = z.z = z.w = 0u;
  *(uint4*)(xmr + ((size_t)n * NPADT + tvrow) * 64 + c * 8) = z;
}

// ---- xmr = bf16(x*mask) row-major [tvp][64] + msum = sum_cin mask ------------
__global__ void k_xmT(const float* __restrict__ x, const float* __restrict__ mask,
                      u16* __restrict__ xmr, float* __restrict__ msum) {
  const int tvb = blockIdx.x, n = blockIdx.y;   // grid (100, 32), block 256
  const int tvl = threadIdx.x & 63, q = threadIdx.x >> 6;  // 4 quads of 16 cin
  const int tv = tvb * 64 + tvl;
  const float* xp = x + ((size_t)n * 64 + q * 16) * TV + tv;
  const float* mp = mask + ((size_t)n * 64 + q * 16) * TV + tv;
  u16 vals[16];
  float msacc = 0.f;
#pragma unroll
  for (int j = 0; j < 16; ++j) {                // coalesced: lanes = consecutive tv
    float xv = xp[(size_t)j * TV];
    float mv = mp[(size_t)j * TV];
    msacc += mv;
    vals[j] = f2bf(xv * mv);
  }
  uint4 lo, hi;
  lo.x = vals[0] | ((u32)vals[1] << 16);  lo.y = vals[2] | ((u32)vals[3] << 16);
  lo.z = vals[4] | ((u32)vals[5] << 16);  lo.w = vals[6] | ((u32)vals[7] << 16);
  hi.x = vals[8] | ((u32)vals[9] << 16);  hi.y = vals[10] | ((u32)vals[11] << 16);
  hi.z = vals[12] | ((u32)vals[13] << 16); hi.w = vals[14] | ((u32)vals[15] << 16);
  u16* dst = xmr + ((size_t)n * NPADT + 100 + tv) * 64 + q * 16;
  *(uint4*)dst = lo;
  *(uint4*)(dst + 8) = hi;
  __shared__ float red[4][64];
  red[q][tvl] = msacc;
  __syncthreads();
  if (q == 0) msum[n * TV + tv] = red[0][tvl] + red[1][tvl] + red[2][tvl] + red[3][tvl];
}

// ---- wb[kc][k=dt*64+cin], bf16, 16B-slot XOR pre-swizzle (by (kc>>1)&3) -----
__global__ void k_w(const float* __restrict__ weight, u16* __restrict__ wb) {
  int i = blockIdx.x * 256 + threadIdx.x;      // 110592
  if (i >= 110592) return;
  int kc = i / KDIM, k = i % KDIM;
  int cin = k & 63, dt = k >> 6;
  float v = weight[(kc * 64 + cin) * 9 + dt];
  int phys = (k & ~31) | ((((k >> 3) & 3) ^ ((kc >> 1) & 3)) << 3) | (k & 7);
  wb[kc * KDIM + phys] = f2bf(v);
}

// ---- per (n,t): upd -> s, mask_ratio, m_bool, Bc ----------------------------
__global__ void k_prep(const float* __restrict__ msum, const float* __restrict__ A_g,
                       float* __restrict__ s_ws, float* __restrict__ mr_ws,
                       float* __restrict__ mb_ws, float* __restrict__ Bc_ws) {
  int b = blockIdx.x;                          // 8192 = n*256 + t
  int n = b >> 8, t = b & 255;
  int tid = threadIdx.x;                       // 64
  __shared__ float uc[25];
  if (tid < 25) {
    float upd = 0.f;
    for (int dt = 0; dt < 9; ++dt) {
      int tt = t + dt - 4;
      if (tt >= 0 && tt < 256) upd += msum[n * TV + tt * 25 + tid];
    }
    float u_c = fminf(fmaxf(upd, 0.f), 1.f);
    float ratio = 576.f / (upd + 1e-8f);
    s_ws[n * TV + t * 25 + tid] = ratio * u_c * u_c;  // coeff of raw in out
    uc[tid] = u_c;
  }
  __syncthreads();
  if (tid < 25) {
    int w = tid;
    float M = 0.f;
    for (int k = 0; k < 3; ++k) {
      float acc = 0.f;
      for (int v = 0; v < 25; ++v) acc += uc[v] * A_g[(k * 25 + v) * 25 + w];
      Bc_ws[((size_t)(n * 3 + k) * 256 + t) * 25 + w] = acc;
      M += acc;
    }
    float mbv = (M != 0.f) ? 1.f : 0.f;
    mr_ws[n * TV + t * 25 + w] = mbv / (M + 1e-8f);
    mb_ws[n * TV + t * 25 + w] = mbv;
  }
}

// ---- FUSED: implicit-GEMM + (k,v)-contraction + coalesced epilogue ----------
// Block (tg, n): 1024 threads, 16 waves = 4(M) x 4(N). Wave cols: wn<3 -> 4
// frags (64 cols), wn=3 -> 1 frag (cols 192-207; 200-207 dead, guarded at
// C-write). acc[3][4] = 48 regs/thread.
__global__ __launch_bounds__(1024, 4) void k_fused(
    const u16* __restrict__ xmr, const u16* __restrict__ wb,
    const float* __restrict__ s_g, const float* __restrict__ A_g,
    const float* __restrict__ Bc_g, const float* __restrict__ mr_g,
    const float* __restrict__ mb_g, const float* __restrict__ bias_g,
    float* __restrict__ out) {
  __shared__ __align__(16) char ring[76800];

  const int tid = threadIdx.x;
  const int tg = blockIdx.x;                  // 0..31 (8-t group)
  const int n = blockIdx.y;                   // 0..31
  const int tv0 = tg * 200;
  const int lane = tid & 63, wid = tid >> 6;
  const int wm = wid >> 2, wn = wid & 3;
  const int lrow = lane & 15, lgrp = lane >> 4;
  const int nf = (wn == 3) ? 1 : 4, colb = wn * 64;

  const u16* xmn = xmr + (size_t)n * NPADT * 64;
  u16* xwin = (u16*)(ring + L_XWIN);

  f32x4 acc[3][4] = {};

  // ---- prologue: stage whole B window (51 loads) + A step 0 (12 loads) ------
  {
    // window rows [tv0, tv0+408) in padded coords; tv0 % 8 == 0 so the
    // logical-slot swizzle key (row & 7) is position-invariant.
    const int srow_g = lane >> 3, sl = (lane & 7) ^ (lane >> 3);  // per-lane
    for (int t = wid; t < 51; t += 16) {
      const u16* src = xmn + ((size_t)(tv0 + t * 8 + srow_g) * 64 + sl * 8);
      gload_lds16(src, xwin + t * 512);
    }
    if (wid < 12) {
      u16* abase = (u16*)(ring + L_ARING);
      const u16* src = wb + (size_t)(wid * 16 + (lane >> 2)) * KDIM + (lane & 3) * 8;
      gload_lds16(src, abase + wid * 512);
    }
  }
  VMCNT(0);
  __builtin_amdgcn_s_barrier();
  asm volatile("" ::: "memory");

  // ---- K-loop: 18 steps; only A staged per step --------------------------
  for (int ks = 0; ks < 18; ++ks) {
    const int cur = ks & 1;
    if (ks < 17 && wid < 12) {                 // stage A(ks+1) into buf cur^1
      u16* abase = (u16*)(ring + L_ARING + (cur ^ 1) * 12288);
      const u16* src = wb + (size_t)(wid * 16 + (lane >> 2)) * KDIM + (ks + 1) * 32 + (lane & 3) * 8;
      gload_lds16(src, abase + wid * 512);
    }

    const u16* abuf = (const u16*)(ring + L_ARING + cur * 12288);
    short8 af[3];
#pragma unroll
    for (int m = 0; m < 3; ++m) {
      int arow = wm * 48 + m * 16 + lrow;
      af[m] = *(const short8*)&abuf[arow * 32 + ((lgrp ^ ((arow >> 1) & 3)) << 3)];
    }
    const int dt = ks >> 1;
    const int rbase = 100 + (dt - 4) * 25 + colb + lrow;   // xwin row for ct=0
    const int slb = (ks & 1) * 4 + lgrp;                   // logical 16B slot
#pragma unroll
    for (int ct = 0; ct < 4; ++ct) {
      if (ct < nf) {
        int srow = rbase + ct * 16;
        short8 bfr = *(const short8*)&xwin[srow * 64 + ((slb ^ (srow & 7)) << 3)];
#pragma unroll
        for (int m = 0; m < 3; ++m)
          acc[m][ct] = __builtin_amdgcn_mfma_f32_16x16x32_bf16(af[m], bfr, acc[m][ct], 0, 0, 0);
      }
    }

    if (ks < 17) {
      VMCNT(0);                        // own A(ks+1) load landed (overlap=compute)
      __builtin_amdgcn_s_barrier();    // all waves done reading abuf[cur]
      asm volatile("" ::: "memory");
    }
  }

  // ---- epilogue: load misc into A-ring alias, then contraction -------------
  __syncthreads();                     // all xwin/A reads done; safe to alias
  float* Asf   = (float*)(ring + L_AS);
  float* Bcsf  = (float*)(ring + L_BCS);
  float* mrsf  = (float*)(ring + L_MRS);
  float* mbsf  = (float*)(ring + L_MBS);
  float* biasf = (float*)(ring + L_BIAS);
  float* ssf   = (float*)(ring + L_SS);
  for (int i = tid; i < 2100; i += 1024) {
    int k = i / 700, r = (i % 700) / 28, w = i % 28;
    Asf[i] = (w < 25) ? A_g[(k * 25 + r) * 25 + w] : 0.f;
  }
  if (tid < 600) {
    int k = tid / 200, t = (tid % 200) / 25, w = tid % 25;
    Bcsf[tid] = Bc_g[((size_t)(n * 3 + k) * 256 + tg * 8 + t) * 25 + w];
  }
  if (tid < 200) {
    mrsf[tid] = mr_g[n * TV + tv0 + tid];
    mbsf[tid] = mb_g[n * TV + tv0 + tid];
    ssf[tid]  = s_g[n * TV + tv0 + tid];
  }
  if (tid >= 512 && tid < 704) biasf[tid - 512] = bias_g[tid - 512];
  __syncthreads();

  u16 (*Cl)[210] = (u16(*)[210])ring;          // alias xwin; stride 105 dw
  float (*Ys)[201] = (float(*)[201])ring;      // alias, barrier-separated
  const int c = tid & 63, th = tid >> 6;
  const int tl = th & 7, wh = th >> 3;         // t-local, w-half
  const int wbase = wh * 12;
  f32x4 a4[3] = {};
  float a24 = 0.f;

  for (int k = 0; k < 3; ++k) {
    __syncthreads();                           // prev Cl reads done
#pragma unroll
    for (int m = 0; m < 3; ++m) {
      int R = wm * 48 + m * 16 + lgrp * 4;
      if ((R >> 6) == k) {
#pragma unroll
        for (int ct = 0; ct < 4; ++ct) {
          if (ct < nf) {
            int col = colb + ct * 16 + lrow;
            if (col < 200) {
#pragma unroll
              for (int r = 0; r < 4; ++r)
                Cl[(R & 63) + r][col] = f2bf(acc[m][ct][r] * ssf[col]);
            }
          }
        }
      }
    }
    __syncthreads();
#pragma unroll 5
    for (int v = 0; v < 25; ++v) {
      float cs = bf2f(Cl[c][tl * 25 + v]);
      const f32x4* ar = (const f32x4*)&Asf[(k * 25 + v) * 28 + wbase];  // broadcast
#pragma unroll
      for (int q = 0; q < 3; ++q) a4[q] += cs * ar[q];
      if (wh) a24 += cs * Asf[(k * 25 + v) * 28 + 24];
    }
  }

  // finalize per-thread y values (w-half each)
  const int nw = 12 + wh;                      // wh=0: w 0-11, wh=1: w 12-24
  float yv[13];
  {
    const float b0 = biasf[c], b1 = biasf[64 + c], b2 = biasf[128 + c];
#pragma unroll
    for (int j = 0; j < 13; ++j) {
      if (j < nw) {
        int w = wbase + j;
        float val = (j < 12) ? a4[j >> 2][j & 3] : a24;
        float bt = b0 * Bcsf[tl * 25 + w] + b1 * Bcsf[200 + tl * 25 + w] +
                   b2 * Bcsf[400 + tl * 25 + w];
        yv[j] = (val + bt) * mrsf[tl * 25 + w];
      }
    }
  }

  // y: two half-c passes through Ys (aliases Cl), coalesced 200-float runs
  const size_t base_n = (size_t)(n * 64) * 6400 + tv0;
#pragma unroll
  for (int half = 0; half < 2; ++half) {
    __syncthreads();                       // Cl/prior-Ys reads complete
    if ((c >> 5) == half) {
      float* yrow = &Ys[c & 31][tl * 25 + wbase];
#pragma unroll
      for (int j = 0; j < 13; ++j)
        if (j < nw) yrow[j] = yv[j];
    }
    __syncthreads();
    for (int i = tid; i < 6400; i += 1024) {
      int ch = i / 200, j = i % 200;
      out[base_n + (size_t)(half * 32 + ch) * 6400 + j] = Ys[ch][j];
    }
  }

  // m_bool: c-independent broadcast, direct coalesced stores
  for (int i = tid; i < 12800; i += 1024) {
    int cc = i / 200, j = i % 200;
    out[MB_OFF + base_n + (size_t)cc * 6400 + j] = mbsf[j];
  }
}

extern "C" void kernel_launch(void* const* d_in, const int* in_sizes, int n_in,
                              void* d_out, int out_size, void* d_ws, size_t ws_size,
                              hipStream_t stream) {
  const float* x      = (const float*)d_in[0];
  const float* A      = (const float*)d_in[1];
  const float* mask   = (const float*)d_in[2];
  const float* weight = (const float*)d_in[3];
  const float* bias   = (const float*)d_in[4];
  float* out = (float*)d_out;
  char* ws = (char*)d_ws;

  u16*   xmr   = (u16*)(ws);
  u16*   wb    = (u16*)(ws + OFF_WB);
  float* msum  = (float*)(ws + OFF_MSUM);
  float* s_ws  = (float*)(ws + OFF_S);
  float* mr_ws = (float*)(ws + OFF_MR);
  float* mb_ws = (float*)(ws + OFF_MB);
  float* Bc_ws = (float*)(ws + OFF_BC);

  k_pad<<<256, 256, 0, stream>>>(xmr);
  k_xmT<<<dim3(100, 32), 256, 0, stream>>>(x, mask, xmr, msum);
  k_w<<<432, 256, 0, stream>>>(weight, wb);
  k_prep<<<8192, 64, 0, stream>>>(msum, A, s_ws, mr_ws, mb_ws, Bc_ws);

  hipMemcpyAsync(out + Y_SIZE, A, 1875 * sizeof(float),
                 hipMemcpyDeviceToDevice, stream);

  k_fused<<<dim3(32, 32), 1024, 0, stream>>>(xmr, wb, s_ws, A, Bc_ws, mr_ws,
                                             mb_ws, bias, out);
}

// Round 9
// 148.837 us; speedup vs baseline: 1.4676x; 1.3664x over previous
//
#include <hip/hip_runtime.h>

// PartialGConv: partial temporal conv (TK=9, pad 4) + mask-ratio + graph einsum.
// FUSED kernel: bf16 implicit-GEMM (MFMA 16x16x32, BM=192 x BN=208(8t) x K=576)
// + MFMA (k,v)-contraction epilogue (r9: replaces the VALU/LDS-broadcast
// contraction that cost ~225 b128/wave). m_bool written by a separate
// coalesced streaming kernel.
//
// ws layout (bytes):
//   xmr  u16[32][6656][64]  @0          x*mask bf16 row-major, padded rows
//   wb   u16[192][576]      @27,262,976 weights bf16, k=dt*64+cin, 16B-slot swizzled
//   msum f32[32][6400]      @27,484,160 sum_cin mask
//   s    f32[32][6400]      @28,303,360 576/(upd+eps)*uc^2
//   mr   f32[32][6400]      @29,122,560 mask_ratio
//   mb   f32[32][6400]      @29,941,760 m_bool
//   Bc   f32[32][3][256][25]@30,760,960 sum_v uc*A[k,v,w]

typedef unsigned short u16;
typedef unsigned int u32;
typedef short short8 __attribute__((ext_vector_type(8)));
typedef float f32x4 __attribute__((ext_vector_type(4)));

#define TV 6400
#define KC 192
#define KDIM 576
#define NPADT 6656          // 100 front pad + 6400 + 156 back pad
#define Y_SIZE 13107200
#define MB_OFF 13109075     // Y_SIZE + 1875

#define OFF_WB   27262976
#define OFF_MSUM 27484160
#define OFF_S    28303360
#define OFF_MR   29122560
#define OFF_MB   29941760
#define OFF_BC   30760960

// LDS map (76,800 B total).  K-loop: xwin [0,52224) + A-ring [52224,76800).
// Epilogue aliases: Pl u16[64][336] @0 (43,008 B); Ys f32[32][201] @0;
// misc @52224: Ab 6144 | Bcs 2400 | mrs 800 | bias 768 | ss 800.
#define L_ARING 52224
#define L_AB    52224
#define L_BCS   58368
#define L_MRS   60768
#define L_BIAS  61568
#define L_SS    62336

#define VMCNT(N) asm volatile("s_waitcnt vmcnt(" #N ")" ::: "memory")

__device__ __forceinline__ u16 f2bf(float f) {
  u32 u = __builtin_bit_cast(u32, f);
  u = (u + 0x7FFFu + ((u >> 16) & 1u)) >> 16;   // RTNE
  return (u16)u;
}
__device__ __forceinline__ float bf2f(u16 h) {
  return __builtin_bit_cast(float, (u32)h << 16);
}
__device__ __forceinline__ void gload_lds16(const u16* g, u16* l) {
  __builtin_amdgcn_global_load_lds(
      (const __attribute__((address_space(1))) u32*)(const void*)g,
      (__attribute__((address_space(3))) u32*)(void*)l, 16, 0, 0);
}

// ---- zero the temporal pad rows of xmr --------------------------------------
__global__ void k_pad(u16* __restrict__ xmr) {
  int i = blockIdx.x * 256 + threadIdx.x;       // 65536 uint4
  if (i >= 65536) return;
  int n = i >> 11, r = i & 2047;                // 256 pad rows x 8 uint4
  int row = r >> 3, c = r & 7;
  int tvrow = (row < 100) ? row : (6400 + row); // front 0..99 / back 6500..6655
  uint4 z; z.x = z.y = z.z = z.w = 0u;
  *(uint4*)(xmr + ((size_t)n * NPADT + tvrow) * 64 + c * 8) = z;
}

// ---- xmr = bf16(x*mask) row-major [tvp][64] + msum = sum_cin mask ------------
__global__ void k_xmT(const float* __restrict__ x, const float* __restrict__ mask,
                      u16* __restrict__ xmr, float* __restrict__ msum) {
  const int tvb = blockIdx.x, n = blockIdx.y;   // grid (100, 32), block 256
  const int tvl = threadIdx.x & 63, q = threadIdx.x >> 6;  // 4 quads of 16 cin
  const int tv = tvb * 64 + tvl;
  const float* xp = x + ((size_t)n * 64 + q * 16) * TV + tv;
  const float* mp = mask + ((size_t)n * 64 + q * 16) * TV + tv;
  u16 vals[16];
  float msacc = 0.f;
#pragma unroll
  for (int j = 0; j < 16; ++j) {                // coalesced: lanes = consecutive tv
    float xv = xp[(size_t)j * TV];
    float mv = mp[(size_t)j * TV];
    msacc += mv;
    vals[j] = f2bf(xv * mv);
  }
  uint4 lo, hi;
  lo.x = vals[0] | ((u32)vals[1] << 16);  lo.y = vals[2] | ((u32)vals[3] << 16);
  lo.z = vals[4] | ((u32)vals[5] << 16);  lo.w = vals[6] | ((u32)vals[7] << 16);
  hi.x = vals[8] | ((u32)vals[9] << 16);  hi.y = vals[10] | ((u32)vals[11] << 16);
  hi.z = vals[12] | ((u32)vals[13] << 16); hi.w = vals[14] | ((u32)vals[15] << 16);
  u16* dst = xmr + ((size_t)n * NPADT + 100 + tv) * 64 + q * 16;
  *(uint4*)dst = lo;
  *(uint4*)(dst + 8) = hi;
  __shared__ float red[4][64];
  red[q][tvl] = msacc;
  __syncthreads();
  if (q == 0) msum[n * TV + tv] = red[0][tvl] + red[1][tvl] + red[2][tvl] + red[3][tvl];
}

// ---- wb[kc][k=dt*64+cin], bf16, 16B-slot XOR pre-swizzle (by (kc>>1)&3) -----
__global__ void k_w(const float* __restrict__ weight, u16* __restrict__ wb) {
  int i = blockIdx.x * 256 + threadIdx.x;      // 110592
  if (i >= 110592) return;
  int kc = i / KDIM, k = i % KDIM;
  int cin = k & 63, dt = k >> 6;
  float v = weight[(kc * 64 + cin) * 9 + dt];
  int phys = (k & ~31) | ((((k >> 3) & 3) ^ ((kc >> 1) & 3)) << 3) | (k & 7);
  wb[kc * KDIM + phys] = f2bf(v);
}

// ---- per (n,t): upd -> s, mask_ratio, m_bool, Bc ----------------------------
__global__ void k_prep(const float* __restrict__ msum, const float* __restrict__ A_g,
                       float* __restrict__ s_ws, float* __restrict__ mr_ws,
                       float* __restrict__ mb_ws, float* __restrict__ Bc_ws) {
  int b = blockIdx.x;                          // 8192 = n*256 + t
  int n = b >> 8, t = b & 255;
  int tid = threadIdx.x;                       // 64
  __shared__ float uc[25];
  if (tid < 25) {
    float upd = 0.f;
    for (int dt = 0; dt < 9; ++dt) {
      int tt = t + dt - 4;
      if (tt >= 0 && tt < 256) upd += msum[n * TV + tt * 25 + tid];
    }
    float u_c = fminf(fmaxf(upd, 0.f), 1.f);
    float ratio = 576.f / (upd + 1e-8f);
    s_ws[n * TV + t * 25 + tid] = ratio * u_c * u_c;  // coeff of raw in out
    uc[tid] = u_c;
  }
  __syncthreads();
  if (tid < 25) {
    int w = tid;
    float M = 0.f;
    for (int k = 0; k < 3; ++k) {
      float acc = 0.f;
      for (int v = 0; v < 25; ++v) acc += uc[v] * A_g[(k * 25 + v) * 25 + w];
      Bc_ws[((size_t)(n * 3 + k) * 256 + t) * 25 + w] = acc;
      M += acc;
    }
    float mbv = (M != 0.f) ? 1.f : 0.f;
    mr_ws[n * TV + t * 25 + w] = mbv / (M + 1e-8f);
    mb_ws[n * TV + t * 25 + w] = mbv;
  }
}

// ---- m_bool: broadcast mb row over all 64 c, coalesced ----------------------
__global__ void k_mb(const float* __restrict__ mb_ws, float* __restrict__ out) {
  const int c = blockIdx.x, n = blockIdx.y;    // grid (64, 32), block 256
  const size_t base = (size_t)MB_OFF + (size_t)(n * 64 + c) * 6400;
  const float* src = mb_ws + n * TV;
  for (int j = threadIdx.x; j < 6400; j += 256)
    out[base + j] = src[j];
}

// ---- FUSED: implicit-GEMM + MFMA (k,v)-contraction + coalesced epilogue -----
// Block (tg, n): 1024 threads, 16 waves = 4(M) x 4(N). Wave cols: wn<3 -> 4
// frags (64 cols), wn=3 -> 1 frag (cols 192-207; 200-207 dead, guarded).
// acc[3][4] = 48 regs/thread.
__global__ __launch_bounds__(1024, 4) void k_fused(
    const u16* __restrict__ xmr, const u16* __restrict__ wb,
    const float* __restrict__ s_g, const float* __restrict__ A_g,
    const float* __restrict__ Bc_g, const float* __restrict__ mr_g,
    const float* __restrict__ bias_g, float* __restrict__ out) {
  __shared__ __align__(16) char ring[76800];

  const int tid = threadIdx.x;
  const int tg = blockIdx.x;                  // 0..31 (8-t group)
  const int n = blockIdx.y;                   // 0..31
  const int tv0 = tg * 200;
  const int lane = tid & 63, wid = tid >> 6;
  const int wm = wid >> 2, wn = wid & 3;
  const int lrow = lane & 15, lgrp = lane >> 4;
  const int nf = (wn == 3) ? 1 : 4, colb = wn * 64;

  const u16* xmn = xmr + (size_t)n * NPADT * 64;
  u16* xwin = (u16*)(ring);

  f32x4 acc[3][4] = {};

  // ---- prologue: stage whole B window (51 loads) + A step 0 (12 loads) ------
  {
    // window rows [tv0, tv0+408) padded; tv0 % 8 == 0 -> swizzle key invariant
    const int srow_g = lane >> 3, sl = (lane & 7) ^ (lane >> 3);  // per-lane
    for (int t = wid; t < 51; t += 16) {
      const u16* src = xmn + ((size_t)(tv0 + t * 8 + srow_g) * 64 + sl * 8);
      gload_lds16(src, xwin + t * 512);
    }
    if (wid < 12) {
      u16* abase = (u16*)(ring + L_ARING);
      const u16* src = wb + (size_t)(wid * 16 + (lane >> 2)) * KDIM + (lane & 3) * 8;
      gload_lds16(src, abase + wid * 512);
    }
  }
  VMCNT(0);
  __builtin_amdgcn_s_barrier();
  asm volatile("" ::: "memory");

  // ---- K-loop: 18 steps; only A staged per step ----------------------------
  for (int ks = 0; ks < 18; ++ks) {
    const int cur = ks & 1;
    if (ks < 17 && wid < 12) {                 // stage A(ks+1) into buf cur^1
      u16* abase = (u16*)(ring + L_ARING + (cur ^ 1) * 12288);
      const u16* src = wb + (size_t)(wid * 16 + (lane >> 2)) * KDIM + (ks + 1) * 32 + (lane & 3) * 8;
      gload_lds16(src, abase + wid * 512);
    }

    const u16* abuf = (const u16*)(ring + L_ARING + cur * 12288);
    short8 af[3];
#pragma unroll
    for (int m = 0; m < 3; ++m) {
      int arow = wm * 48 + m * 16 + lrow;
      af[m] = *(const short8*)&abuf[arow * 32 + ((lgrp ^ ((arow >> 1) & 3)) << 3)];
    }
    const int dt = ks >> 1;
    const int rbase = 100 + (dt - 4) * 25 + colb + lrow;   // xwin row for ct=0
    const int slb = (ks & 1) * 4 + lgrp;                   // logical 16B slot
#pragma unroll
    for (int ct = 0; ct < 4; ++ct) {
      if (ct < nf) {
        int srow = rbase + ct * 16;
        short8 bfr = *(const short8*)&xwin[srow * 64 + ((slb ^ (srow & 7)) << 3)];
#pragma unroll
        for (int m = 0; m < 3; ++m)
          acc[m][ct] = __builtin_amdgcn_mfma_f32_16x16x32_bf16(af[m], bfr, acc[m][ct], 0, 0, 0);
      }
    }

    if (ks < 17) {
      VMCNT(0);                        // own A(ks+1) load landed (overlap=compute)
      __builtin_amdgcn_s_barrier();    // all waves done reading abuf[cur]
      asm volatile("" ::: "memory");
    }
  }

  // ---- epilogue setup: zero Pl, stage Ab/Bcs/mrs/bias/ss -------------------
  __syncthreads();                     // all xwin/abuf reads done; safe to alias
  u16*   Plu   = (u16*)ring;           // [64][336]: tcol = t*40+v, pads zero
  u16*   Abu   = (u16*)(ring + L_AB);  // [3k][2nt][16w][32v] bf16 B-frag layout
  float* Bcsf  = (float*)(ring + L_BCS);
  float* mrsf  = (float*)(ring + L_MRS);
  float* biasf = (float*)(ring + L_BIAS);
  float* ssf   = (float*)(ring + L_SS);
  for (int i = tid; i < 10752; i += 1024) ((u32*)ring)[i] = 0;  // zero Pl (43KB)
  for (int i = tid; i < 3072; i += 1024) {
    int kk = i >> 10, r = i & 1023;
    int nt = r >> 9, rr = r & 511, wl = rr >> 5, v = rr & 31;
    int w = nt * 16 + wl;
    float val = (v < 25 && w < 25) ? A_g[(kk * 25 + v) * 25 + w] : 0.f;
    Abu[i] = f2bf(val);
  }
  if (tid < 600) {
    int k = tid / 200, t = (tid % 200) / 25, w = tid % 25;
    Bcsf[tid] = Bc_g[((size_t)(n * 3 + k) * 256 + tg * 8 + t) * 25 + w];
  }
  if (tid < 200) {
    mrsf[tid] = mr_g[n * TV + tv0 + tid];
    ssf[tid]  = s_g[n * TV + tv0 + tid];
  }
  if (tid >= 512 && tid < 704) biasf[tid - 512] = bias_g[tid - 512];
  __syncthreads();

  // ---- MFMA contraction: y(ct,w) = sum_v P(ct,v) * A(v,w), per-k -----------
  f32x4 yacc[2][2] = {};
  for (int k = 0; k < 3; ++k) {
    // stage Pl_k = bf16(acc * s) for rows of this k
#pragma unroll
    for (int m = 0; m < 3; ++m) {
      int R = wm * 48 + m * 16 + lgrp * 4;
      if ((R >> 6) == k) {
        int cb = R & 63;
#pragma unroll
        for (int ct = 0; ct < 4; ++ct) {
          if (ct < nf) {
            int col = colb + ct * 16 + lrow;
            if (col < 200) {
              int t = col / 25, v = col - t * 25;
              float sv = ssf[col];
              int tc = t * 40 + v;
#pragma unroll
              for (int r = 0; r < 4; ++r)
                Plu[(cb + r) * 336 + tc] = f2bf(acc[m][ct][r] * sv);
            }
          }
        }
      }
    }
    __syncthreads();
    // contraction MFMAs: wave owns M-tiles {wid*2, wid*2+1}
    short8 pb[2];
#pragma unroll
    for (int nt = 0; nt < 2; ++nt)
      pb[nt] = *(const short8*)&Abu[((k * 2 + nt) * 16 + lrow) * 32 + lgrp * 8];
#pragma unroll
    for (int mi = 0; mi < 2; ++mi) {
      int mt = wid * 2 + mi;
      const short8 pa = *(const short8*)
          &Plu[(mt * 2 + (lrow >> 3)) * 336 + (lrow & 7) * 40 + lgrp * 8];
#pragma unroll
      for (int nt = 0; nt < 2; ++nt)
        yacc[mi][nt] = __builtin_amdgcn_mfma_f32_16x16x32_bf16(pa, pb[nt], yacc[mi][nt], 0, 0, 0);
    }
    __syncthreads();                   // before next k overwrites Pl
  }

  // ---- finalize + transposed coalesced y writes ----------------------------
  // yacc[mi][nt][r]: row ct = (wid*2+mi)*16 + lgrp*4 + r, col w = nt*16 + lrow
  float (*Ysf)[201] = (float(*)[201])ring;     // aliases Pl, barrier-separated
  const size_t base_n = (size_t)(n * 64) * 6400 + tv0;
#pragma unroll
  for (int half = 0; half < 2; ++half) {
    __syncthreads();
    if ((wid >> 3) == half) {
#pragma unroll
      for (int mi = 0; mi < 2; ++mi)
#pragma unroll
        for (int nt = 0; nt < 2; ++nt) {
          int w = nt * 16 + lrow;
          if (w < 25) {
#pragma unroll
            for (int r = 0; r < 4; ++r) {
              int ct = (wid * 2 + mi) * 16 + lgrp * 4 + r;
              int c = ct >> 3, t = ct & 7;
              float bt = biasf[c] * Bcsf[t * 25 + w] +
                         biasf[64 + c] * Bcsf[200 + t * 25 + w] +
                         biasf[128 + c] * Bcsf[400 + t * 25 + w];
              Ysf[c & 31][t * 25 + w] = (yacc[mi][nt][r] + bt) * mrsf[t * 25 + w];
            }
          }
        }
    }
    __syncthreads();
    for (int i = tid; i < 6400; i += 1024) {
      int ch = i / 200, j = i % 200;
      out[base_n + (size_t)(half * 32 + ch) * 6400 + j] = Ysf[ch][j];
    }
  }
}

extern "C" void kernel_launch(void* const* d_in, const int* in_sizes, int n_in,
                              void* d_out, int out_size, void* d_ws, size_t ws_size,
                              hipStream_t stream) {
  const float* x      = (const float*)d_in[0];
  const float* A      = (const float*)d_in[1];
  const float* mask   = (const float*)d_in[2];
  const float* weight = (const float*)d_in[3];
  const float* bias   = (const float*)d_in[4];
  float* out = (float*)d_out;
  char* ws = (char*)d_ws;

  u16*   xmr   = (u16*)(ws);
  u16*   wb    = (u16*)(ws + OFF_WB);
  float* msum  = (float*)(ws + OFF_MSUM);
  float* s_ws  = (float*)(ws + OFF_S);
  float* mr_ws = (float*)(ws + OFF_MR);
  float* mb_ws = (float*)(ws + OFF_MB);
  float* Bc_ws = (float*)(ws + OFF_BC);

  k_pad<<<256, 256, 0, stream>>>(xmr);
  k_xmT<<<dim3(100, 32), 256, 0, stream>>>(x, mask, xmr, msum);
  k_w<<<432, 256, 0, stream>>>(weight, wb);
  k_prep<<<8192, 64, 0, stream>>>(msum, A, s_ws, mr_ws, mb_ws, Bc_ws);

  hipMemcpyAsync(out + Y_SIZE, A, 1875 * sizeof(float),
                 hipMemcpyDeviceToDevice, stream);

  k_mb<<<dim3(64, 32), 256, 0, stream>>>(mb_ws, out);
  k_fused<<<dim3(32, 32), 1024, 0, stream>>>(xmr, wb, s_ws, A, Bc_ws, mr_ws,
                                             bias, out);
}